// Round 7
// baseline (298.139 us; speedup 1.0000x reference)
//
#include <hip/hip_runtime.h>
#include <hip/hip_fp16.h>

#define N_NODES 50000
#define F 128
#define SCAN_B 1024
#define SCAN_NB ((N_NODES + SCAN_B - 1) / SCAN_B)   // 49
#define NBKT ((N_NODES + 15) / 16)                  // 3125 fill buckets
#define LDK 136                                     // padded LDS row (fp16), 16B-mult

typedef _Float16 f16x8 __attribute__((ext_vector_type(8)));
typedef float    f32x4 __attribute__((ext_vector_type(4)));

// ---- degree histogram over real edges ----
__global__ void k_count(const int* __restrict__ dst, int E, int* __restrict__ deg) {
    int i = blockIdx.x * blockDim.x + threadIdx.x;
    if (i < E) atomicAdd(&deg[dst[i]], 1);
}

// ---- per-block sum of 1024 degrees -> partials[block] ----
__global__ __launch_bounds__(1024) void k_bsum(const int* __restrict__ deg,
                                               int* __restrict__ partials) {
    const int i = blockIdx.x * SCAN_B + threadIdx.x;
    int v = (i < N_NODES) ? deg[i] : 0;
#pragma unroll
    for (int d = 1; d < 64; d <<= 1) v += __shfl_xor(v, d);
    __shared__ int ws[16];
    if ((threadIdx.x & 63) == 0) ws[threadIdx.x >> 6] = v;
    __syncthreads();
    if (threadIdx.x < 16) {
        int s = ws[threadIdx.x];
#pragma unroll
        for (int d = 1; d < 16; d <<= 1) s += __shfl_xor(s, d);
        if (threadIdx.x == 0) partials[blockIdx.x] = s;
    }
}

// ---- 1-wave exclusive scan of the 49 partials ----
__global__ void k_pscan(int* __restrict__ partials) {
    const int t = threadIdx.x;
    const int x = (t < SCAN_NB) ? partials[t] : 0;
    int inc = x;
#pragma unroll
    for (int d = 1; d < 64; d <<= 1) {
        const int u = __shfl_up(inc, d);
        if (t >= d) inc += u;
    }
    if (t < SCAN_NB) partials[t] = inc - x;          // exclusive
}

// ---- block-local scan + global offset: offsets/cursor/dinv ----
__global__ __launch_bounds__(1024) void k_offsets(const int* __restrict__ deg,
                                                  const int* __restrict__ partials,
                                                  int* __restrict__ offsets,
                                                  int* __restrict__ cursor,
                                                  float* __restrict__ dinv, int E) {
    const int i = blockIdx.x * SCAN_B + threadIdx.x;
    const int d = (i < N_NODES) ? deg[i] : 0;
    const int lane = threadIdx.x & 63, wid = threadIdx.x >> 6;
    int inc = d;
#pragma unroll
    for (int dd = 1; dd < 64; dd <<= 1) {
        const int u = __shfl_up(inc, dd);
        if (lane >= dd) inc += u;
    }
    __shared__ int wsum[16], wpre[16];
    if (lane == 63) wsum[wid] = inc;
    __syncthreads();
    if (threadIdx.x < 16) {
        const int s = wsum[threadIdx.x];
        int is = s;
#pragma unroll
        for (int dd = 1; dd < 16; dd <<= 1) {
            const int u = __shfl_up(is, dd);
            if (threadIdx.x >= dd) is += u;
        }
        wpre[threadIdx.x] = is - s;
    }
    __syncthreads();
    const int ex = (inc - d) + wpre[wid] + partials[blockIdx.x];
    if (i <= N_NODES) offsets[i] = ex;               // offsets[N_NODES] == E
    if (i < N_NODES) {
        cursor[i] = ex;
        dinv[i]   = rsqrtf((float)(d + 1));          // +1 self loop
    }
}

// ---- bucket cursors: bcur[b] = offsets[b*16] ----
__global__ void k_binit(const int* __restrict__ offsets, int* __restrict__ bcur) {
    int b = blockIdx.x * blockDim.x + threadIdx.x;
    if (b < NBKT) bcur[b] = offsets[b * 16];
}

// ---- fill phase 1: append packed (src, d&15) into the dst-bucket region ----
__global__ void k_fill1(const int* __restrict__ src, const int* __restrict__ dst, int E,
                        int* __restrict__ bcur, unsigned* __restrict__ pairs) {
    int i = blockIdx.x * blockDim.x + threadIdx.x;
    if (i < E) {
        const int d   = dst[i];
        const int pos = atomicAdd(&bcur[d >> 4], 1);
        pairs[pos] = (unsigned)src[i] | ((unsigned)(d & 15) << 16);
    }
}

// ---- fill phase 2: within-bucket scatter (L2-hot ~1KB windows) ----
__global__ __launch_bounds__(256) void k_fill2(const int* __restrict__ offsets,
                                               const unsigned* __restrict__ pairs,
                                               int* __restrict__ cursor,
                                               int* __restrict__ csr_src) {
    const int b  = blockIdx.x;
    const int lo = offsets[b * 16];
    const int hi = offsets[b * 16 + 16];
    for (int i = lo + threadIdx.x; i < hi; i += 256) {
        const unsigned p = pairs[i];
        const int d = (b << 4) | (int)(p >> 16);
        const int pos = atomicAdd(&cursor[d], 1);
        csr_src[pos] = (int)(p & 0xFFFFu);
    }
}

// ---- W prep: Wt[n][k] = (fp16) W[k][n] ----
__global__ void k_wprep(const float* __restrict__ W, __half* __restrict__ Wt) {
    for (int i = threadIdx.x; i < F * F; i += 256) {
        const int k = i >> 7, n = i & 127;
        Wt[n * F + k] = __float2half(W[i]);
    }
}

// ---- MFMA GEMM: Hs(fp16) = dinv[row] * (X @ W), X fp32 -> fp16 on stage ----
// 256 thr / 4 waves; tile 64 rows x 128 cols, K=128. Wave w: rows w*16..+16,
// 8 n-tiles of 16x16x32_f16. Xs/Ws padded to LDK=136 (bank-conflict-free b128).
__global__ __launch_bounds__(256) void k_gemm(const float* __restrict__ X,
                                              const __half* __restrict__ Wt,
                                              const float* __restrict__ dinv,
                                              __half* __restrict__ Hs, int nrows) {
    __shared__ __half Xs[64 * LDK];                  // 17.4 KB
    __shared__ __half Ws[128 * LDK];                 // 34.8 KB
    const int t    = threadIdx.x;
    const int wid  = t >> 6;
    const int lane = t & 63;
    const int r0   = blockIdx.x * 64;

    // stage Wt (fp16, n-major): 2 thr per n-row, 8 uint4 each
    {
        const uint4* Wg = (const uint4*)Wt;          // 16 uint4 per n-row
        const int n = t >> 1, c0 = (t & 1) * 8;
        uint4* drow = (uint4*)&Ws[n * LDK];
#pragma unroll
        for (int j = 0; j < 8; ++j) drow[c0 + j] = Wg[n * 16 + c0 + j];
    }
    // stage X tile -> fp16: 4 thr per row, 8 float4 each
    {
        const int xr = t >> 2, c0 = (t & 3) * 32;    // c0 in fp16/float units
        const int grow = min(r0 + xr, nrows - 1);    // clamp: garbage ok, no fault
        const float4* Xg = (const float4*)(X + (size_t)grow * F);
        __half2* xd = (__half2*)&Xs[xr * LDK + c0];
#pragma unroll
        for (int j = 0; j < 8; ++j) {
            const float4 v = Xg[c0 / 4 + j];
            xd[2 * j]     = __float22half2_rn(make_float2(v.x, v.y));
            xd[2 * j + 1] = __float22half2_rn(make_float2(v.z, v.w));
        }
    }
    __syncthreads();

    const int m  = lane & 15;                        // row within 16 / col within 16
    const int kg = lane >> 4;                        // k-group 0..3
    f32x4 acc[8] = {};
#pragma unroll
    for (int kk = 0; kk < 4; ++kk) {
        const f16x8 a = *(const f16x8*)&Xs[(wid * 16 + m) * LDK + kk * 32 + kg * 8];
#pragma unroll
        for (int nt = 0; nt < 8; ++nt) {
            const f16x8 bfr = *(const f16x8*)&Ws[(nt * 16 + m) * LDK + kk * 32 + kg * 8];
            acc[nt] = __builtin_amdgcn_mfma_f32_16x16x32_f16(a, bfr, acc[nt], 0, 0, 0);
        }
    }
    __syncthreads();                                 // done reading Xs

    // epilogue: scale + pack fp16 into Xs, then coalesced copy-out
    {
        const int lr0 = wid * 16 + kg * 4;           // 4 output rows per lane
#pragma unroll
        for (int r = 0; r < 4; ++r) {
            const int lr = lr0 + r;
            const float dn = dinv[min(r0 + lr, nrows - 1)];
#pragma unroll
            for (int nt = 0; nt < 8; ++nt)
                Xs[lr * LDK + nt * 16 + m] = __float2half(dn * acc[nt][r]);
        }
    }
    __syncthreads();
    {
        const int row = t >> 2, c0 = (t & 3) * 4;    // c0 in uint4 units
        const int g = r0 + row;
        if (g < nrows) {
            const uint4* srow = (const uint4*)&Xs[row * LDK];
            uint4* drow = (uint4*)(Hs + (size_t)g * F);
#pragma unroll
            for (int j = 0; j < 4; ++j) drow[c0 + j] = srow[c0 + j];
        }
    }
}

// ---- node gather (fp16 rows, fp32 accumulate) ----
__global__ __launch_bounds__(256) void k_gather(const int* __restrict__ offsets,
                                                const int* __restrict__ csr_src,
                                                const __half* __restrict__ Hs,
                                                const float* __restrict__ dinv,
                                                const float* __restrict__ b,
                                                float* __restrict__ out) {
    const int tid = blockIdx.x * blockDim.x + threadIdx.x;
    const int g   = tid >> 5;
    const int l32 = threadIdx.x & 31;
    const int ng  = (gridDim.x * blockDim.x) >> 5;
    const uint2* __restrict__ Hv = (const uint2*)Hs; // row = 32 x uint2 (4 fp16)
    float4* __restrict__ outv = (float4*)out;
    const float4 bb = ((const float4*)b)[l32];
    for (int n = g; n < N_NODES; n += ng) {
        const int beg = offsets[n], end = offsets[n + 1];
        float4 a0 = make_float4(0.f, 0.f, 0.f, 0.f);
        float4 a1 = make_float4(0.f, 0.f, 0.f, 0.f);
        float4 a2 = make_float4(0.f, 0.f, 0.f, 0.f);
        float4 a3 = make_float4(0.f, 0.f, 0.f, 0.f);
        {
            const uint2 raw = Hv[n * 32 + l32];
            const float2 f0 = __half22float2(*(const __half2*)&raw.x);
            const float2 f1 = __half22float2(*(const __half2*)&raw.y);
            a0.x += f0.x; a0.y += f0.y; a0.z += f1.x; a0.w += f1.y;
        }
        int e = beg;
        for (; e + 3 < end; e += 4) {
            const int s0 = csr_src[e];
            const int s1 = csr_src[e + 1];
            const int s2 = csr_src[e + 2];
            const int s3 = csr_src[e + 3];
            const uint2 r0 = Hv[s0 * 32 + l32];
            const uint2 r1 = Hv[s1 * 32 + l32];
            const uint2 r2 = Hv[s2 * 32 + l32];
            const uint2 r3 = Hv[s3 * 32 + l32];
            float2 f;
            f = __half22float2(*(const __half2*)&r0.x); a0.x += f.x; a0.y += f.y;
            f = __half22float2(*(const __half2*)&r0.y); a0.z += f.x; a0.w += f.y;
            f = __half22float2(*(const __half2*)&r1.x); a1.x += f.x; a1.y += f.y;
            f = __half22float2(*(const __half2*)&r1.y); a1.z += f.x; a1.w += f.y;
            f = __half22float2(*(const __half2*)&r2.x); a2.x += f.x; a2.y += f.y;
            f = __half22float2(*(const __half2*)&r2.y); a2.z += f.x; a2.w += f.y;
            f = __half22float2(*(const __half2*)&r3.x); a3.x += f.x; a3.y += f.y;
            f = __half22float2(*(const __half2*)&r3.y); a3.z += f.x; a3.w += f.y;
        }
        for (; e < end; ++e) {
            const uint2 r0 = Hv[csr_src[e] * 32 + l32];
            float2 f;
            f = __half22float2(*(const __half2*)&r0.x); a1.x += f.x; a1.y += f.y;
            f = __half22float2(*(const __half2*)&r0.y); a1.z += f.x; a1.w += f.y;
        }
        const float dn = dinv[n];
        float4 o;
        o.x = fmaxf(fmaf(dn, (a0.x + a1.x) + (a2.x + a3.x), bb.x), 0.f);
        o.y = fmaxf(fmaf(dn, (a0.y + a1.y) + (a2.y + a3.y), bb.y), 0.f);
        o.z = fmaxf(fmaf(dn, (a0.z + a1.z) + (a2.z + a3.z), bb.z), 0.f);
        o.w = fmaxf(fmaf(dn, (a0.w + a1.w) + (a2.w + a3.w), bb.w), 0.f);
        outv[n * 32 + l32] = o;
    }
}

extern "C" void kernel_launch(void* const* d_in, const int* in_sizes, int n_in,
                              void* d_out, int out_size, void* d_ws, size_t ws_size,
                              hipStream_t stream) {
    const float* x  = (const float*)d_in[0];
    const int*   ei = (const int*)  d_in[1];
    const float* W1 = (const float*)d_in[2];
    const float* b1 = (const float*)d_in[3];
    const float* W2 = (const float*)d_in[4];
    const float* b2 = (const float*)d_in[5];
    float* out = (float*)d_out;

    const int E = in_sizes[1] / 2;        // 800000
    const int* srcp = ei;                 // edge_index[0]
    const int* dstp = ei + E;             // edge_index[1]

    // ---- workspace carve-up (prefix = 1000004 ints -> 16B-aligned after) ----
    int*      deg      = (int*)d_ws;                  // 50000
    int*      offsets  = deg + N_NODES;               // 50004 (N+1 used, padded)
    int*      cursor   = offsets + N_NODES + 4;       // 50000
    int*      csr_src  = cursor + N_NODES;            // 800000
    float*    dinv     = (float*)(csr_src + E);       // 50000
    __half*   Hs       = (__half*)(dinv + N_NODES);   // N*F fp16, 16B-aligned
    __half*   Wt1      = Hs + (size_t)N_NODES * F;    // 16384 fp16 (16B-aligned)
    __half*   Wt2      = Wt1 + F * F;                 // 16384 fp16
    int*      partials = (int*)(Wt2 + F * F);         // SCAN_NB
    int*      bcur     = partials + 64;               // NBKT
    unsigned* pairs    = (unsigned*)(bcur + NBKT);    // E

    // ---- weight prep (independent) ----
    k_wprep<<<1, 256, 0, stream>>>(W1, Wt1);
    k_wprep<<<1, 256, 0, stream>>>(W2, Wt2);

    // ---- CSR build (shared by both layers) ----
    hipMemsetAsync(deg, 0, N_NODES * sizeof(int), stream);
    k_count  <<<(E + 255) / 256, 256, 0, stream>>>(dstp, E, deg);
    k_bsum   <<<SCAN_NB, SCAN_B, 0, stream>>>(deg, partials);
    k_pscan  <<<1, 64, 0, stream>>>(partials);
    k_offsets<<<SCAN_NB, SCAN_B, 0, stream>>>(deg, partials, offsets, cursor, dinv, E);
    k_binit  <<<(NBKT + 255) / 256, 256, 0, stream>>>(offsets, bcur);
    k_fill1  <<<(E + 255) / 256, 256, 0, stream>>>(srcp, dstp, E, bcur, pairs);
    k_fill2  <<<NBKT, 256, 0, stream>>>(offsets, pairs, cursor, csr_src);

    const int gemm_blocks = (N_NODES + 63) / 64;     // 782

    // ---- layer 1 ----
    k_gemm  <<<gemm_blocks, 256, 0, stream>>>(x, Wt1, dinv, Hs, N_NODES);
    k_gather<<<2048, 256, 0, stream>>>(offsets, csr_src, Hs, dinv, b1, out);

    // ---- layer 2 ----
    k_gemm  <<<gemm_blocks, 256, 0, stream>>>(out, Wt2, dinv, Hs, N_NODES);
    k_gather<<<2048, 256, 0, stream>>>(offsets, csr_src, Hs, dinv, b2, out);
}

// Round 8
// 243.536 us; speedup vs baseline: 1.2242x; 1.2242x over previous
//
#include <hip/hip_runtime.h>
#include <hip/hip_fp16.h>

#define N_NODES 50000
#define F 128
#define LDK 136                                     // padded LDS row (fp16), 16B-mult

typedef _Float16 f16x8 __attribute__((ext_vector_type(8)));
typedef float    f32x4 __attribute__((ext_vector_type(4)));

// ---- per-region degree histogram: region r = blockIdx&7 (XCD-local atomics) ----
__global__ void k_count8(const int* __restrict__ dst, int E, int* __restrict__ deg8) {
    const int i = blockIdx.x * 256 + threadIdx.x;
    const int r = blockIdx.x & 7;
    if (i < E) atomicAdd(&deg8[r * N_NODES + dst[i]], 1);
}

// ---- generic per-block sum (1024/block) for scan ----
__global__ __launch_bounds__(1024) void k_bsum(const int* __restrict__ a, int NT,
                                               int* __restrict__ partials) {
    const int i = blockIdx.x * 1024 + threadIdx.x;
    int v = (i < NT) ? a[i] : 0;
#pragma unroll
    for (int d = 1; d < 64; d <<= 1) v += __shfl_xor(v, d);
    __shared__ int ws[16];
    if ((threadIdx.x & 63) == 0) ws[threadIdx.x >> 6] = v;
    __syncthreads();
    if (threadIdx.x < 16) {
        int s = ws[threadIdx.x];
#pragma unroll
        for (int d = 1; d < 16; d <<= 1) s += __shfl_xor(s, d);
        if (threadIdx.x == 0) partials[blockIdx.x] = s;
    }
}

// ---- 1-wave in-place exclusive scan of up to 64*CH partials ----
__global__ void k_pscan(int* __restrict__ p, int count) {
    const int t  = threadIdx.x;
    const int CH = (count + 63) / 64;
    const int lo = t * CH, hi = min(lo + CH, count);
    int s = 0;
    for (int i = lo; i < hi; ++i) s += p[i];
    int inc = s;
#pragma unroll
    for (int d = 1; d < 64; d <<= 1) {
        const int u = __shfl_up(inc, d);
        if (t >= d) inc += u;
    }
    int run = inc - s;                               // exclusive prefix
    for (int i = lo; i < hi; ++i) { const int v = p[i]; p[i] = run; run += v; }
}

// ---- scan-apply: offs = exclusive scan of a (+ sentinel), optional cursor copy ----
__global__ __launch_bounds__(1024) void k_scanapply(const int* __restrict__ a,
                                                    const int* __restrict__ partials,
                                                    int* __restrict__ offs,
                                                    int* __restrict__ cur, int NT) {
    const int i = blockIdx.x * 1024 + threadIdx.x;
    const int d = (i < NT) ? a[i] : 0;
    const int lane = threadIdx.x & 63, wid = threadIdx.x >> 6;
    int inc = d;
#pragma unroll
    for (int dd = 1; dd < 64; dd <<= 1) {
        const int u = __shfl_up(inc, dd);
        if (lane >= dd) inc += u;
    }
    __shared__ int wsum[16], wpre[16];
    if (lane == 63) wsum[wid] = inc;
    __syncthreads();
    if (threadIdx.x < 16) {
        const int s = wsum[threadIdx.x];
        int is = s;
#pragma unroll
        for (int dd = 1; dd < 16; dd <<= 1) {
            const int u = __shfl_up(is, dd);
            if (threadIdx.x >= dd) is += u;
        }
        wpre[threadIdx.x] = is - s;
    }
    __syncthreads();
    const int ex = (inc - d) + wpre[wid] + partials[blockIdx.x];
    if (i <= NT) offs[i] = ex;
    if (cur != nullptr && i < NT) cur[i] = ex;
}

// ---- canonical degree = sum of 8 regions; dinv = rsqrt(deg+1) ----
__global__ void k_degsum(const int* __restrict__ deg8, int* __restrict__ deg,
                         float* __restrict__ dinv) {
    const int n = blockIdx.x * blockDim.x + threadIdx.x;
    if (n < N_NODES) {
        int s = 0;
#pragma unroll
        for (int r = 0; r < 8; ++r) s += deg8[r * N_NODES + n];
        deg[n]  = s;
        dinv[n] = rsqrtf((float)(s + 1));            // +1 self loop
    }
}

// ---- fill: scatter src(u16) into this block's XCD-private region ----
__global__ void k_fill8(const int* __restrict__ src, const int* __restrict__ dst, int E,
                        int* __restrict__ cur8, unsigned short* __restrict__ csr8) {
    const int i = blockIdx.x * 256 + threadIdx.x;
    const int r = blockIdx.x & 7;                    // must match k_count8's mapping
    if (i < E) {
        const int d   = dst[i];
        const int pos = atomicAdd(&cur8[r * N_NODES + d], 1);
        csr8[pos] = (unsigned short)src[i];
    }
}

// ---- merge 8 per-node segments into canonical CSR (coalesced both sides) ----
__global__ __launch_bounds__(256) void k_reorder(const int* __restrict__ off8,
                                                 const int* __restrict__ offs,
                                                 const unsigned short* __restrict__ csr8,
                                                 unsigned short* __restrict__ csr) {
    const int g  = (blockIdx.x * 256 + threadIdx.x) >> 5;
    const int l  = threadIdx.x & 31;
    const int ng = (gridDim.x * 256) >> 5;
    for (int n = g; n < N_NODES; n += ng) {
        int o = offs[n];
#pragma unroll
        for (int r = 0; r < 8; ++r) {
            const int s   = off8[r * N_NODES + n];
            const int len = off8[r * N_NODES + n + 1] - s;   // contiguous flat scan
            for (int j = l; j < len; j += 32) csr[o + j] = csr8[s + j];
            o += len;
        }
    }
}

// ---- W prep: Wt[n][k] = (fp16) W[k][n] ----
__global__ void k_wprep(const float* __restrict__ W, __half* __restrict__ Wt) {
    for (int i = threadIdx.x; i < F * F; i += 256) {
        const int k = i >> 7, n = i & 127;
        Wt[n * F + k] = __float2half(W[i]);
    }
}

// ---- MFMA GEMM: Hs(fp16) = dinv[row] * (X @ W), X fp32 -> fp16 on stage ----
__global__ __launch_bounds__(256) void k_gemm(const float* __restrict__ X,
                                              const __half* __restrict__ Wt,
                                              const float* __restrict__ dinv,
                                              __half* __restrict__ Hs, int nrows) {
    __shared__ __half Xs[64 * LDK];                  // 17.4 KB
    __shared__ __half Ws[128 * LDK];                 // 34.8 KB
    const int t    = threadIdx.x;
    const int wid  = t >> 6;
    const int lane = t & 63;
    const int r0   = blockIdx.x * 64;

    {   // stage Wt (fp16, n-major): 2 thr per n-row, 8 uint4 each
        const uint4* Wg = (const uint4*)Wt;
        const int n = t >> 1, c0 = (t & 1) * 8;
        uint4* drow = (uint4*)&Ws[n * LDK];
#pragma unroll
        for (int j = 0; j < 8; ++j) drow[c0 + j] = Wg[n * 16 + c0 + j];
    }
    {   // stage X tile -> fp16: 4 thr per row, 8 float4 each
        const int xr = t >> 2, c0 = (t & 3) * 32;
        const int grow = min(r0 + xr, nrows - 1);
        const float4* Xg = (const float4*)(X + (size_t)grow * F);
        __half2* xd = (__half2*)&Xs[xr * LDK + c0];
#pragma unroll
        for (int j = 0; j < 8; ++j) {
            const float4 v = Xg[c0 / 4 + j];
            xd[2 * j]     = __float22half2_rn(make_float2(v.x, v.y));
            xd[2 * j + 1] = __float22half2_rn(make_float2(v.z, v.w));
        }
    }
    __syncthreads();

    const int m  = lane & 15;
    const int kg = lane >> 4;
    f32x4 acc[8] = {};
#pragma unroll
    for (int kk = 0; kk < 4; ++kk) {
        const f16x8 a = *(const f16x8*)&Xs[(wid * 16 + m) * LDK + kk * 32 + kg * 8];
#pragma unroll
        for (int nt = 0; nt < 8; ++nt) {
            const f16x8 bfr = *(const f16x8*)&Ws[(nt * 16 + m) * LDK + kk * 32 + kg * 8];
            acc[nt] = __builtin_amdgcn_mfma_f32_16x16x32_f16(a, bfr, acc[nt], 0, 0, 0);
        }
    }
    __syncthreads();

    {   // epilogue: scale + pack fp16 into Xs
        const int lr0 = wid * 16 + kg * 4;
#pragma unroll
        for (int r = 0; r < 4; ++r) {
            const int lr = lr0 + r;
            const float dn = dinv[min(r0 + lr, nrows - 1)];
#pragma unroll
            for (int nt = 0; nt < 8; ++nt)
                Xs[lr * LDK + nt * 16 + m] = __float2half(dn * acc[nt][r]);
        }
    }
    __syncthreads();
    {   // coalesced copy-out
        const int row = t >> 2, c0 = (t & 3) * 4;
        const int g = r0 + row;
        if (g < nrows) {
            const uint4* srow = (const uint4*)&Xs[row * LDK];
            uint4* drow = (uint4*)(Hs + (size_t)g * F);
#pragma unroll
            for (int j = 0; j < 4; ++j) drow[c0 + j] = srow[c0 + j];
        }
    }
}

// ---- node gather (fp16 rows, fp32 accumulate, u16 indices) ----
__global__ __launch_bounds__(256) void k_gather(const int* __restrict__ offsets,
                                                const unsigned short* __restrict__ csr,
                                                const __half* __restrict__ Hs,
                                                const float* __restrict__ dinv,
                                                const float* __restrict__ b,
                                                float* __restrict__ out) {
    const int tid = blockIdx.x * blockDim.x + threadIdx.x;
    const int g   = tid >> 5;
    const int l32 = threadIdx.x & 31;
    const int ng  = (gridDim.x * blockDim.x) >> 5;
    const uint2* __restrict__ Hv = (const uint2*)Hs;
    float4* __restrict__ outv = (float4*)out;
    const float4 bb = ((const float4*)b)[l32];
    for (int n = g; n < N_NODES; n += ng) {
        const int beg = offsets[n], end = offsets[n + 1];
        float4 a0 = make_float4(0.f, 0.f, 0.f, 0.f);
        float4 a1 = make_float4(0.f, 0.f, 0.f, 0.f);
        float4 a2 = make_float4(0.f, 0.f, 0.f, 0.f);
        float4 a3 = make_float4(0.f, 0.f, 0.f, 0.f);
        {
            const uint2 raw = Hv[n * 32 + l32];
            const float2 f0 = __half22float2(*(const __half2*)&raw.x);
            const float2 f1 = __half22float2(*(const __half2*)&raw.y);
            a0.x += f0.x; a0.y += f0.y; a0.z += f1.x; a0.w += f1.y;
        }
        int e = beg;
        for (; e + 3 < end; e += 4) {
            const int s0 = csr[e];
            const int s1 = csr[e + 1];
            const int s2 = csr[e + 2];
            const int s3 = csr[e + 3];
            const uint2 r0 = Hv[s0 * 32 + l32];
            const uint2 r1 = Hv[s1 * 32 + l32];
            const uint2 r2 = Hv[s2 * 32 + l32];
            const uint2 r3 = Hv[s3 * 32 + l32];
            float2 f;
            f = __half22float2(*(const __half2*)&r0.x); a0.x += f.x; a0.y += f.y;
            f = __half22float2(*(const __half2*)&r0.y); a0.z += f.x; a0.w += f.y;
            f = __half22float2(*(const __half2*)&r1.x); a1.x += f.x; a1.y += f.y;
            f = __half22float2(*(const __half2*)&r1.y); a1.z += f.x; a1.w += f.y;
            f = __half22float2(*(const __half2*)&r2.x); a2.x += f.x; a2.y += f.y;
            f = __half22float2(*(const __half2*)&r2.y); a2.z += f.x; a2.w += f.y;
            f = __half22float2(*(const __half2*)&r3.x); a3.x += f.x; a3.y += f.y;
            f = __half22float2(*(const __half2*)&r3.y); a3.z += f.x; a3.w += f.y;
        }
        for (; e < end; ++e) {
            const uint2 r0 = Hv[csr[e] * 32 + l32];
            float2 f;
            f = __half22float2(*(const __half2*)&r0.x); a1.x += f.x; a1.y += f.y;
            f = __half22float2(*(const __half2*)&r0.y); a1.z += f.x; a1.w += f.y;
        }
        const float dn = dinv[n];
        float4 o;
        o.x = fmaxf(fmaf(dn, (a0.x + a1.x) + (a2.x + a3.x), bb.x), 0.f);
        o.y = fmaxf(fmaf(dn, (a0.y + a1.y) + (a2.y + a3.y), bb.y), 0.f);
        o.z = fmaxf(fmaf(dn, (a0.z + a1.z) + (a2.z + a3.z), bb.z), 0.f);
        o.w = fmaxf(fmaf(dn, (a0.w + a1.w) + (a2.w + a3.w), bb.w), 0.f);
        outv[n * 32 + l32] = o;
    }
}

extern "C" void kernel_launch(void* const* d_in, const int* in_sizes, int n_in,
                              void* d_out, int out_size, void* d_ws, size_t ws_size,
                              hipStream_t stream) {
    const float* x  = (const float*)d_in[0];
    const int*   ei = (const int*)  d_in[1];
    const float* W1 = (const float*)d_in[2];
    const float* b1 = (const float*)d_in[3];
    const float* W2 = (const float*)d_in[4];
    const float* b2 = (const float*)d_in[5];
    float* out = (float*)d_out;

    const int E = in_sizes[1] / 2;        // 800000
    const int* srcp = ei;                 // edge_index[0]
    const int* dstp = ei + E;             // edge_index[1]
    const int N8 = 8 * N_NODES;           // 400000

    // ---- workspace carve-up (all 16B-aligned boundaries) ----
    int*            deg8 = (int*)d_ws;                    // 400000
    int*            off8 = deg8 + N8;                     // 400001 (+7 pad)
    int*            cur8 = off8 + N8 + 8;                 // 400000
    int*            deg  = cur8 + N8;                     // 50000
    int*            offs = deg + N_NODES;                 // 50001 (+7 pad)
    float*          dinv = (float*)(offs + N_NODES + 8);  // 50000
    int*            part = (int*)(dinv + N_NODES);        // 1024
    unsigned short* csr8 = (unsigned short*)(part + 1024);   // E u16
    unsigned short* csr  = csr8 + E;                      // E u16
    __half*         Hs   = (__half*)(csr + E);            // N*F fp16
    __half*         Wt1  = Hs + (size_t)N_NODES * F;      // F*F fp16
    __half*         Wt2  = Wt1 + F * F;                   // F*F fp16

    const int nb_e  = (E + 255) / 256;                    // 3125
    const int nb_n8 = (N8 + 1023) / 1024;                 // 391
    const int nb_n  = (N_NODES + 1023) / 1024;            // 49

    // ---- weight prep ----
    k_wprep<<<1, 256, 0, stream>>>(W1, Wt1);
    k_wprep<<<1, 256, 0, stream>>>(W2, Wt2);

    // ---- CSR build: per-XCD regions, then merge ----
    hipMemsetAsync(deg8, 0, N8 * sizeof(int), stream);
    k_count8  <<<nb_e, 256, 0, stream>>>(dstp, E, deg8);
    k_bsum    <<<nb_n8, 1024, 0, stream>>>(deg8, N8, part);
    k_pscan   <<<1, 64, 0, stream>>>(part, nb_n8);
    k_scanapply<<<nb_n8, 1024, 0, stream>>>(deg8, part, off8, cur8, N8);
    k_degsum  <<<(N_NODES + 255) / 256, 256, 0, stream>>>(deg8, deg, dinv);
    k_bsum    <<<nb_n, 1024, 0, stream>>>(deg, N_NODES, part);
    k_pscan   <<<1, 64, 0, stream>>>(part, nb_n);
    k_scanapply<<<nb_n, 1024, 0, stream>>>(deg, part, offs, nullptr, N_NODES);
    k_fill8   <<<nb_e, 256, 0, stream>>>(srcp, dstp, E, cur8, csr8);
    k_reorder <<<6250, 256, 0, stream>>>(off8, offs, csr8, csr);

    const int gemm_blocks = (N_NODES + 63) / 64;          // 782

    // ---- layer 1 ----
    k_gemm  <<<gemm_blocks, 256, 0, stream>>>(x, Wt1, dinv, Hs, N_NODES);
    k_gather<<<2048, 256, 0, stream>>>(offs, csr, Hs, dinv, b1, out);

    // ---- layer 2 ----
    k_gemm  <<<gemm_blocks, 256, 0, stream>>>(out, Wt2, dinv, Hs, N_NODES);
    k_gather<<<2048, 256, 0, stream>>>(offs, csr, Hs, dinv, b2, out);
}

// Round 9
// 213.382 us; speedup vs baseline: 1.3972x; 1.1413x over previous
//
#include <hip/hip_runtime.h>
#include <hip/hip_fp16.h>

#define N_NODES 50000
#define F 128
#define N8 (8 * N_NODES)                            // 400000
#define LDK 136                                     // padded LDS row (fp16), 16B-mult

typedef _Float16 f16x8 __attribute__((ext_vector_type(8)));
typedef float    f32x4 __attribute__((ext_vector_type(4)));

// ---- prep: zero deg8 + transpose/convert both weight matrices ----
// blocks [0,1563): zero deg8; block 1563: Wt1; block 1564: Wt2.
__global__ void k_prep(int* __restrict__ deg8,
                       const float* __restrict__ W1, const float* __restrict__ W2,
                       __half* __restrict__ Wt1, __half* __restrict__ Wt2) {
    const int b = blockIdx.x;
    if (b < 1563) {
        const int i = b * 256 + threadIdx.x;
        if (i < N8) deg8[i] = 0;
    } else {
        const float* W  = (b == 1563) ? W1 : W2;
        __half*      Wt = (b == 1563) ? Wt1 : Wt2;
        for (int i = threadIdx.x; i < F * F; i += 256) {
            const int k = i >> 7, n = i & 127;
            Wt[n * F + k] = __float2half(W[i]);     // Wt[n][k] = W[k][n]
        }
    }
}

// ---- per-region degree histogram: region r = blockIdx&7 (XCD-local atomics) ----
__global__ void k_count8(const int* __restrict__ dst, int E, int* __restrict__ deg8) {
    const int i = blockIdx.x * 256 + threadIdx.x;
    const int r = blockIdx.x & 7;
    if (i < E) atomicAdd(&deg8[r * N_NODES + dst[i]], 1);
}

// ---- deg[n] = sum_r deg8[r][n]; dinv; block partial sums for the scan ----
__global__ __launch_bounds__(1024) void k_bsumdeg(const int* __restrict__ deg8,
                                                  int* __restrict__ deg,
                                                  float* __restrict__ dinv,
                                                  int* __restrict__ partials) {
    const int i = blockIdx.x * 1024 + threadIdx.x;
    int s = 0;
    if (i < N_NODES) {
#pragma unroll
        for (int r = 0; r < 8; ++r) s += deg8[r * N_NODES + i];
        deg[i]  = s;
        dinv[i] = rsqrtf((float)(s + 1));            // +1 self loop
    }
    int v = s;
#pragma unroll
    for (int d = 1; d < 64; d <<= 1) v += __shfl_xor(v, d);
    __shared__ int ws[16];
    if ((threadIdx.x & 63) == 0) ws[threadIdx.x >> 6] = v;
    __syncthreads();
    if (threadIdx.x < 16) {
        int t = ws[threadIdx.x];
#pragma unroll
        for (int d = 1; d < 16; d <<= 1) t += __shfl_xor(t, d);
        if (threadIdx.x == 0) partials[blockIdx.x] = t;
    }
}

// ---- 1-wave in-place exclusive scan of up to 64*CH partials ----
__global__ void k_pscan(int* __restrict__ p, int count) {
    const int t  = threadIdx.x;
    const int CH = (count + 63) / 64;
    const int lo = t * CH, hi = min(lo + CH, count);
    int s = 0;
    for (int i = lo; i < hi; ++i) s += p[i];
    int inc = s;
#pragma unroll
    for (int d = 1; d < 64; d <<= 1) {
        const int u = __shfl_up(inc, d);
        if (t >= d) inc += u;
    }
    int run = inc - s;                               // exclusive prefix
    for (int i = lo; i < hi; ++i) { const int v = p[i]; p[i] = run; run += v; }
}

// ---- offs = exclusive scan of deg (+ sentinel at N_NODES) ----
__global__ __launch_bounds__(1024) void k_scanapply(const int* __restrict__ a,
                                                    const int* __restrict__ partials,
                                                    int* __restrict__ offs, int NT) {
    const int i = blockIdx.x * 1024 + threadIdx.x;
    const int d = (i < NT) ? a[i] : 0;
    const int lane = threadIdx.x & 63, wid = threadIdx.x >> 6;
    int inc = d;
#pragma unroll
    for (int dd = 1; dd < 64; dd <<= 1) {
        const int u = __shfl_up(inc, dd);
        if (lane >= dd) inc += u;
    }
    __shared__ int wsum[16], wpre[16];
    if (lane == 63) wsum[wid] = inc;
    __syncthreads();
    if (threadIdx.x < 16) {
        const int s = wsum[threadIdx.x];
        int is = s;
#pragma unroll
        for (int dd = 1; dd < 16; dd <<= 1) {
            const int u = __shfl_up(is, dd);
            if (threadIdx.x >= dd) is += u;
        }
        wpre[threadIdx.x] = is - s;
    }
    __syncthreads();
    const int ex = (inc - d) + wpre[wid] + partials[blockIdx.x];
    if (i <= NT) offs[i] = ex;
}

// ---- cur8[r][n] = offs[n] + sum_{r'<r} deg8[r'][n]  (canonical positions) ----
__global__ void k_curinit(const int* __restrict__ offs, const int* __restrict__ deg8,
                          int* __restrict__ cur8) {
    const int n = blockIdx.x * blockDim.x + threadIdx.x;
    if (n < N_NODES) {
        int o = offs[n];
#pragma unroll
        for (int r = 0; r < 8; ++r) {
            cur8[r * N_NODES + n] = o;
            o += deg8[r * N_NODES + n];
        }
    }
}

// ---- fill: XCD-local cursor atomics hand out final canonical csr slots ----
__global__ void k_fill8(const int* __restrict__ src, const int* __restrict__ dst, int E,
                        int* __restrict__ cur8, unsigned short* __restrict__ csr) {
    const int i = blockIdx.x * 256 + threadIdx.x;
    const int r = blockIdx.x & 7;                    // must match k_count8's mapping
    if (i < E) {
        const int d   = dst[i];
        const int pos = atomicAdd(&cur8[r * N_NODES + d], 1);
        csr[pos] = (unsigned short)src[i];
    }
}

// ---- MFMA GEMM: Hs(fp16) = dinv[row] * (X @ W); 512 thr, 128-row tiles ----
__global__ __launch_bounds__(512) void k_gemm(const float* __restrict__ X,
                                              const __half* __restrict__ Wt,
                                              const float* __restrict__ dinv,
                                              __half* __restrict__ Hs, int nrows) {
    __shared__ __half Xs[128 * LDK];                 // 34.8 KB
    __shared__ __half Ws[128 * LDK];                 // 34.8 KB
    const int t    = threadIdx.x;
    const int wid  = t >> 6;                         // 0..7
    const int lane = t & 63;
    const int r0   = blockIdx.x * 128;

    {   // stage Wt (fp16, n-major): 4 thr per n-row, 4 uint4 each
        const uint4* Wg = (const uint4*)Wt;          // 16 uint4 per n-row
        const int n = t >> 2, c0 = (t & 3) * 4;
        uint4* drow = (uint4*)&Ws[n * LDK];
#pragma unroll
        for (int j = 0; j < 4; ++j) drow[c0 + j] = Wg[n * 16 + c0 + j];
    }
    {   // stage X tile -> fp16: 4 thr per row, 8 float4 each
        const int xr = t >> 2, c0 = (t & 3) * 32;    // c0 in fp16/float units
        const int grow = min(r0 + xr, nrows - 1);    // clamp: garbage ok, no fault
        const float4* Xg = (const float4*)(X + (size_t)grow * F);
        __half2* xd = (__half2*)&Xs[xr * LDK + c0];
#pragma unroll
        for (int j = 0; j < 8; ++j) {
            const float4 v = Xg[c0 / 4 + j];
            xd[2 * j]     = __float22half2_rn(make_float2(v.x, v.y));
            xd[2 * j + 1] = __float22half2_rn(make_float2(v.z, v.w));
        }
    }
    __syncthreads();

    const int m  = lane & 15;
    const int kg = lane >> 4;
    f32x4 acc[8] = {};
#pragma unroll
    for (int kk = 0; kk < 4; ++kk) {
        const f16x8 a = *(const f16x8*)&Xs[(wid * 16 + m) * LDK + kk * 32 + kg * 8];
#pragma unroll
        for (int nt = 0; nt < 8; ++nt) {
            const f16x8 bfr = *(const f16x8*)&Ws[(nt * 16 + m) * LDK + kk * 32 + kg * 8];
            acc[nt] = __builtin_amdgcn_mfma_f32_16x16x32_f16(a, bfr, acc[nt], 0, 0, 0);
        }
    }
    __syncthreads();                                 // done reading Xs

    {   // epilogue: scale + pack fp16 into Xs
        const int lr0 = wid * 16 + kg * 4;           // 4 output rows per lane
#pragma unroll
        for (int r = 0; r < 4; ++r) {
            const int lr = lr0 + r;
            const float dn = dinv[min(r0 + lr, nrows - 1)];
#pragma unroll
            for (int nt = 0; nt < 8; ++nt)
                Xs[lr * LDK + nt * 16 + m] = __float2half(dn * acc[nt][r]);
        }
    }
    __syncthreads();
    {   // coalesced copy-out: 4 thr per row, 4 uint4 each
        const int row = t >> 2, c0 = (t & 3) * 4;
        const int g = r0 + row;
        if (g < nrows) {
            const uint4* srow = (const uint4*)&Xs[row * LDK];
            uint4* drow = (uint4*)(Hs + (size_t)g * F);
#pragma unroll
            for (int j = 0; j < 4; ++j) drow[c0 + j] = srow[c0 + j];
        }
    }
}

// ---- node gather (fp16 rows, fp32 accumulate, u16 indices) ----
__global__ __launch_bounds__(256) void k_gather(const int* __restrict__ offsets,
                                                const unsigned short* __restrict__ csr,
                                                const __half* __restrict__ Hs,
                                                const float* __restrict__ dinv,
                                                const float* __restrict__ b,
                                                float* __restrict__ out) {
    const int tid = blockIdx.x * blockDim.x + threadIdx.x;
    const int g   = tid >> 5;
    const int l32 = threadIdx.x & 31;
    const int ng  = (gridDim.x * blockDim.x) >> 5;
    const uint2* __restrict__ Hv = (const uint2*)Hs;
    float4* __restrict__ outv = (float4*)out;
    const float4 bb = ((const float4*)b)[l32];
    for (int n = g; n < N_NODES; n += ng) {
        const int beg = offsets[n], end = offsets[n + 1];
        float4 a0 = make_float4(0.f, 0.f, 0.f, 0.f);
        float4 a1 = make_float4(0.f, 0.f, 0.f, 0.f);
        float4 a2 = make_float4(0.f, 0.f, 0.f, 0.f);
        float4 a3 = make_float4(0.f, 0.f, 0.f, 0.f);
        {
            const uint2 raw = Hv[n * 32 + l32];
            const float2 f0 = __half22float2(*(const __half2*)&raw.x);
            const float2 f1 = __half22float2(*(const __half2*)&raw.y);
            a0.x += f0.x; a0.y += f0.y; a0.z += f1.x; a0.w += f1.y;
        }
        int e = beg;
        for (; e + 3 < end; e += 4) {
            const int s0 = csr[e];
            const int s1 = csr[e + 1];
            const int s2 = csr[e + 2];
            const int s3 = csr[e + 3];
            const uint2 r0 = Hv[s0 * 32 + l32];
            const uint2 r1 = Hv[s1 * 32 + l32];
            const uint2 r2 = Hv[s2 * 32 + l32];
            const uint2 r3 = Hv[s3 * 32 + l32];
            float2 f;
            f = __half22float2(*(const __half2*)&r0.x); a0.x += f.x; a0.y += f.y;
            f = __half22float2(*(const __half2*)&r0.y); a0.z += f.x; a0.w += f.y;
            f = __half22float2(*(const __half2*)&r1.x); a1.x += f.x; a1.y += f.y;
            f = __half22float2(*(const __half2*)&r1.y); a1.z += f.x; a1.w += f.y;
            f = __half22float2(*(const __half2*)&r2.x); a2.x += f.x; a2.y += f.y;
            f = __half22float2(*(const __half2*)&r2.y); a2.z += f.x; a2.w += f.y;
            f = __half22float2(*(const __half2*)&r3.x); a3.x += f.x; a3.y += f.y;
            f = __half22float2(*(const __half2*)&r3.y); a3.z += f.x; a3.w += f.y;
        }
        for (; e < end; ++e) {
            const uint2 r0 = Hv[csr[e] * 32 + l32];
            float2 f;
            f = __half22float2(*(const __half2*)&r0.x); a1.x += f.x; a1.y += f.y;
            f = __half22float2(*(const __half2*)&r0.y); a1.z += f.x; a1.w += f.y;
        }
        const float dn = dinv[n];
        float4 o;
        o.x = fmaxf(fmaf(dn, (a0.x + a1.x) + (a2.x + a3.x), bb.x), 0.f);
        o.y = fmaxf(fmaf(dn, (a0.y + a1.y) + (a2.y + a3.y), bb.y), 0.f);
        o.z = fmaxf(fmaf(dn, (a0.z + a1.z) + (a2.z + a3.z), bb.z), 0.f);
        o.w = fmaxf(fmaf(dn, (a0.w + a1.w) + (a2.w + a3.w), bb.w), 0.f);
        outv[n * 32 + l32] = o;
    }
}

extern "C" void kernel_launch(void* const* d_in, const int* in_sizes, int n_in,
                              void* d_out, int out_size, void* d_ws, size_t ws_size,
                              hipStream_t stream) {
    const float* x  = (const float*)d_in[0];
    const int*   ei = (const int*)  d_in[1];
    const float* W1 = (const float*)d_in[2];
    const float* b1 = (const float*)d_in[3];
    const float* W2 = (const float*)d_in[4];
    const float* b2 = (const float*)d_in[5];
    float* out = (float*)d_out;

    const int E = in_sizes[1] / 2;        // 800000
    const int* srcp = ei;                 // edge_index[0]
    const int* dstp = ei + E;             // edge_index[1]

    // ---- workspace carve-up (16B-aligned boundaries) ----
    int*            deg8 = (int*)d_ws;                    // 400000
    int*            cur8 = deg8 + N8;                     // 400000
    int*            deg  = cur8 + N8;                     // 50000
    int*            offs = deg + N_NODES;                 // 50001 (+7 pad)
    float*          dinv = (float*)(offs + N_NODES + 8);  // 50000
    int*            part = (int*)(dinv + N_NODES);        // 64
    unsigned short* csr  = (unsigned short*)(part + 64);  // E u16 (1.6MB, 16B-ok)
    __half*         Hs   = (__half*)(csr + E);            // N*F fp16
    __half*         Wt1  = Hs + (size_t)N_NODES * F;      // F*F fp16
    __half*         Wt2  = Wt1 + F * F;                   // F*F fp16

    const int nb_e = (E + 255) / 256;                     // 3125
    const int nb_n = (N_NODES + 1023) / 1024;             // 49

    // ---- CSR build: 7 dispatches, canonical positions, no reorder ----
    k_prep    <<<1565, 256, 0, stream>>>(deg8, W1, W2, Wt1, Wt2);
    k_count8  <<<nb_e, 256, 0, stream>>>(dstp, E, deg8);
    k_bsumdeg <<<nb_n, 1024, 0, stream>>>(deg8, deg, dinv, part);
    k_pscan   <<<1, 64, 0, stream>>>(part, nb_n);
    k_scanapply<<<nb_n, 1024, 0, stream>>>(deg, part, offs, N_NODES);
    k_curinit <<<(N_NODES + 255) / 256, 256, 0, stream>>>(offs, deg8, cur8);
    k_fill8   <<<nb_e, 256, 0, stream>>>(srcp, dstp, E, cur8, csr);

    const int gemm_blocks = (N_NODES + 127) / 128;        // 391

    // ---- layer 1 ----
    k_gemm  <<<gemm_blocks, 512, 0, stream>>>(x, Wt1, dinv, Hs, N_NODES);
    k_gather<<<2048, 256, 0, stream>>>(offs, csr, Hs, dinv, b1, out);

    // ---- layer 2 ----
    k_gemm  <<<gemm_blocks, 512, 0, stream>>>(out, Wt2, dinv, Hs, N_NODES);
    k_gather<<<2048, 256, 0, stream>>>(offs, csr, Hs, dinv, b2, out);
}